// Round 1
// baseline (161.704 us; speedup 1.0000x reference)
//
#include <hip/hip_runtime.h>
#include <math.h>

#define NS 64
#define NV 16
#define NHS 32
#define NHV 16

__device__ __forceinline__ float silu_f(float x){ return x * (1.0f / (1.0f + __expf(-x))); }

// monotone float->uint mapping for atomicMax-based float max
__device__ __forceinline__ unsigned f2key(float f){
    unsigned b = __float_as_uint(f);
    return (b & 0x80000000u) ? ~b : (b | 0x80000000u);
}
__device__ __forceinline__ float key2f(unsigned k){
    return __uint_as_float((k & 0x80000000u) ? (k & 0x7FFFFFFFu) : ~k);
}

// Per-node precompute: pack[n] = {A(n), fpp[3], frame[9], pos[3]}  (16 floats, 64B)
// A(n) = sum_h silu(Ws@s)[h]*Wattn[s_off+h] + sum_{h<16,d} silu((Wv@v)^T scalarized)[h,d]*Wattn[v_off+h*3+d]
// fpp[d] = sum_c pos[c]*frame[c][d]
__global__ __launch_bounds__(256) void node_pack_kernel(
    const float* __restrict__ node_s,   // [N,64]
    const float* __restrict__ node_v,   // [N,16,3]
    const float* __restrict__ frame,    // [N,3,3]
    const float* __restrict__ pos,      // [N,3]
    const float* __restrict__ Ws,       // [32,64]
    const float* __restrict__ Wv,       // [16,16]
    const float* __restrict__ Wattn,    // [166]
    int s_off, int v_off,
    float* __restrict__ pack,           // [N,16]
    int N)
{
    __shared__ float lws[NHS*NS];        // 8KB
    __shared__ float lwv[NHV*NV];        // 1KB
    __shared__ float lwa[NHS + NHV*3];   // 80 floats
    int tid = threadIdx.x;
    for (int i = tid; i < NHS*NS; i += 256) lws[i] = Ws[i];
    if (tid < NHV*NV) lwv[tid] = Wv[tid];
    if (tid < NHS) lwa[tid] = Wattn[s_off + tid];
    if (tid < NHV*3) lwa[NHS + tid] = Wattn[v_off + tid];
    __syncthreads();

    int n = blockIdx.x * 256 + tid;
    if (n >= N) return;

    float s[NS];
    {
        const float4* sp = (const float4*)(node_s + (size_t)n * NS);
        #pragma unroll
        for (int i = 0; i < NS/4; i++){
            float4 t = sp[i];
            s[4*i+0]=t.x; s[4*i+1]=t.y; s[4*i+2]=t.z; s[4*i+3]=t.w;
        }
    }
    float acc = 0.0f;
    const float4* lws4 = (const float4*)lws;
    #pragma unroll 4
    for (int h = 0; h < NHS; h++){
        float d = 0.0f;
        #pragma unroll
        for (int k4 = 0; k4 < NS/4; k4++){
            float4 w = lws4[h*(NS/4) + k4];
            d += s[4*k4+0]*w.x + s[4*k4+1]*w.y + s[4*k4+2]*w.z + s[4*k4+3]*w.w;
        }
        acc += silu_f(d) * lwa[h];
    }

    float v[NV*3];
    {
        const float4* vp = (const float4*)(node_v + (size_t)n * (NV*3));
        #pragma unroll
        for (int i = 0; i < (NV*3)/4; i++){
            float4 t = vp[i];
            v[4*i+0]=t.x; v[4*i+1]=t.y; v[4*i+2]=t.z; v[4*i+3]=t.w;
        }
    }
    float fvp0[NHV], fvp1[NHV], fvp2[NHV];
    #pragma unroll 2
    for (int h = 0; h < NHV; h++){
        float a0=0.f, a1=0.f, a2=0.f;
        #pragma unroll
        for (int vv = 0; vv < NV; vv++){
            float w = lwv[h*NV + vv];
            a0 += v[vv*3+0]*w;
            a1 += v[vv*3+1]*w;
            a2 += v[vv*3+2]*w;
        }
        fvp0[h]=a0; fvp1[h]=a1; fvp2[h]=a2;
    }

    float ff[9];
    #pragma unroll
    for (int i = 0; i < 9; i++) ff[i] = frame[(size_t)n*9 + i];
    float ps[3];
    #pragma unroll
    for (int i = 0; i < 3; i++) ps[i] = pos[(size_t)n*3 + i];

    #pragma unroll
    for (int h = 0; h < NHV; h++){
        #pragma unroll
        for (int d = 0; d < 3; d++){
            float t = fvp0[h]*ff[0*3+d] + fvp1[h]*ff[1*3+d] + fvp2[h]*ff[2*3+d];
            acc += silu_f(t) * lwa[NHS + h*3 + d];
        }
    }
    float fpp0 = ps[0]*ff[0] + ps[1]*ff[3] + ps[2]*ff[6];
    float fpp1 = ps[0]*ff[1] + ps[1]*ff[4] + ps[2]*ff[7];
    float fpp2 = ps[0]*ff[2] + ps[1]*ff[5] + ps[2]*ff[8];

    float4* pk = (float4*)(pack + (size_t)n * 16);
    pk[0] = make_float4(acc,  fpp0,  fpp1,  fpp2);
    pk[1] = make_float4(ff[0], ff[1], ff[2], ff[3]);
    pk[2] = make_float4(ff[4], ff[5], ff[6], ff[7]);
    pk[3] = make_float4(ff[8], ps[0], ps[1], ps[2]);
}

// Per-edge: raw = A[i0] + B[i1] + 6 silu pos-diff cross terms; segment max via atomicMax
__global__ __launch_bounds__(256) void edge_raw_kernel(
    const int* __restrict__ idx,
    const float* __restrict__ packA,
    const float* __restrict__ packB,
    const float* __restrict__ Wattn,
    float* __restrict__ raw,
    unsigned* __restrict__ segmax,
    int E)
{
    int e = blockIdx.x * 256 + threadIdx.x;
    if (e >= E) return;
    int i0 = idx[e];
    int i1 = idx[E + e];
    const float4* pa = (const float4*)(packA + (size_t)i0 * 16);
    const float4* pb = (const float4*)(packB + (size_t)i1 * 16);
    float4 a0 = pa[0], a1 = pa[1], a2 = pa[2], a3 = pa[3];
    float4 b0 = pb[0], b1 = pb[1], b2 = pb[2], b3 = pb[3];

    float r = a0.x + b0.x;
    // to_pos = b3.yzw ; from_pos = a3.yzw
    float tp0=b3.y, tp1=b3.z, tp2=b3.w;
    float fp0=a3.y, fp1=a3.z, fp2=a3.w;
    // pdf[d] = to_pos . ff[:,d] - fpp[d];  ff row-major [c][d]: a1=ff0..3, a2=ff4..7, a3.x=ff8
    float pdf0 = tp0*a1.x + tp1*a1.w + tp2*a2.z - a0.y;
    float pdf1 = tp0*a1.y + tp1*a2.x + tp2*a2.w - a0.z;
    float pdf2 = tp0*a1.z + tp1*a2.y + tp2*a3.x - a0.w;
    // pdt[d] = from_pos . tf[:,d] - tpp[d]
    float pdt0 = fp0*b1.x + fp1*b1.w + fp2*b2.z - b0.y;
    float pdt1 = fp0*b1.y + fp1*b2.x + fp2*b2.w - b0.z;
    float pdt2 = fp0*b1.z + fp1*b2.y + fp2*b3.x - b0.w;

    r += silu_f(pdf0) * Wattn[112] + silu_f(pdf1) * Wattn[113] + silu_f(pdf2) * Wattn[114];
    r += silu_f(pdt0) * Wattn[163] + silu_f(pdt1) * Wattn[164] + silu_f(pdt2) * Wattn[165];

    raw[e] = r;
    atomicMax(&segmax[i0], f2key(r));
}

__global__ __launch_bounds__(256) void edge_exp_kernel(
    const int* __restrict__ idx,
    const float* __restrict__ raw,
    const unsigned* __restrict__ segmax,
    float* __restrict__ ex,
    float* __restrict__ den,
    int E)
{
    int e = blockIdx.x * 256 + threadIdx.x;
    if (e >= E) return;
    int i0 = idx[e];
    float m = key2f(segmax[i0]);
    float v = __expf(raw[e] - m);
    ex[e] = v;
    atomicAdd(&den[i0], v);
}

__global__ __launch_bounds__(256) void edge_out_kernel(
    const int* __restrict__ idx,
    const float* __restrict__ ex,
    const float* __restrict__ den,
    float* __restrict__ out,
    int E)
{
    int e = blockIdx.x * 256 + threadIdx.x;
    if (e >= E) return;
    int i0 = idx[e];
    out[e] = ex[e] / den[i0];
}

extern "C" void kernel_launch(void* const* d_in, const int* in_sizes, int n_in,
                              void* d_out, int out_size, void* d_ws, size_t ws_size,
                              hipStream_t stream)
{
    const float* from_s  = (const float*)d_in[0];
    const float* from_v  = (const float*)d_in[1];
    const float* to_s    = (const float*)d_in[2];
    const float* to_v    = (const float*)d_in[3];
    const float* from_fr = (const float*)d_in[4];
    const float* to_fr   = (const float*)d_in[5];
    const float* from_p  = (const float*)d_in[6];
    const float* to_p    = (const float*)d_in[7];
    const float* Wfs     = (const float*)d_in[8];
    const float* Wts     = (const float*)d_in[9];
    const float* Wfv     = (const float*)d_in[10];
    const float* Wtv     = (const float*)d_in[11];
    const float* Wattn   = (const float*)d_in[12];
    const int*   idx     = (const int*)d_in[13];

    int N = in_sizes[0] / NS;
    int E = in_sizes[13] / 2;
    float* out = (float*)d_out;

    char* ws = (char*)d_ws;
    size_t packBytes = (size_t)N * 16 * sizeof(float);
    float*    packA  = (float*)(ws);
    float*    packB  = (float*)(ws + packBytes);
    float*    raw    = (float*)(ws + 2*packBytes);
    float*    ex     = (float*)(ws + 2*packBytes + (size_t)E*4);
    unsigned* segmax = (unsigned*)(ws + 2*packBytes + (size_t)E*8);
    float*    den    = (float*)(ws + 2*packBytes + (size_t)E*8 + (size_t)N*4);

    // zero segmax (key 0 == -inf sentinel) and den in one shot (contiguous)
    hipMemsetAsync(segmax, 0, (size_t)N * 8, stream);

    int nb_n = (N + 255) / 256;
    node_pack_kernel<<<nb_n, 256, 0, stream>>>(from_s, from_v, from_fr, from_p,
                                               Wfs, Wfv, Wattn, 0, 64, packA, N);
    node_pack_kernel<<<nb_n, 256, 0, stream>>>(to_s, to_v, to_fr, to_p,
                                               Wts, Wtv, Wattn, 32, 115, packB, N);

    int nb_e = (E + 255) / 256;
    edge_raw_kernel<<<nb_e, 256, 0, stream>>>(idx, packA, packB, Wattn, raw, segmax, E);
    edge_exp_kernel<<<nb_e, 256, 0, stream>>>(idx, raw, segmax, ex, den, E);
    edge_out_kernel<<<nb_e, 256, 0, stream>>>(idx, ex, den, out, E);
}

// Round 2
// 93.614 us; speedup vs baseline: 1.7274x; 1.7274x over previous
//
#include <hip/hip_runtime.h>
#include <math.h>

#define NS 64
#define NV 16
#define NHS 32
#define NHV 16
#define NPB 16           // nodes per block (16 lanes/node, 256 threads)
#define WS_PAD 68        // padded row stride for Ws in LDS (breaks bank conflict)
#define WV_PAD 17

__device__ __forceinline__ float silu_f(float x){ return x * (1.0f / (1.0f + __expf(-x))); }

// Per-node precompute: pack[n] = {A(n), fpp[3], frame[9], pos[3]}  (16 floats, 64B)
// blockIdx.y selects side (0 = from/A, 1 = to/B).
__global__ __launch_bounds__(256) void node_pack_kernel(
    const float* __restrict__ from_s, const float* __restrict__ from_v,
    const float* __restrict__ from_fr, const float* __restrict__ from_p,
    const float* __restrict__ to_s, const float* __restrict__ to_v,
    const float* __restrict__ to_fr, const float* __restrict__ to_p,
    const float* __restrict__ Wfs, const float* __restrict__ Wts,
    const float* __restrict__ Wfv, const float* __restrict__ Wtv,
    const float* __restrict__ Wattn,
    float* __restrict__ packA, float* __restrict__ packB,
    int N)
{
    const int side = blockIdx.y;
    const float* node_s = side ? to_s  : from_s;
    const float* node_v = side ? to_v  : from_v;
    const float* frame  = side ? to_fr : from_fr;
    const float* pos    = side ? to_p  : from_p;
    const float* Ws     = side ? Wts   : Wfs;
    const float* Wv     = side ? Wtv   : Wfv;
    const int    s_off  = side ? 32 : 0;
    const int    v_off  = side ? 115 : 64;
    float*       pack   = side ? packB : packA;

    __shared__ float lws[NHS * WS_PAD];     // 32x68
    __shared__ float lwv[NHV * WV_PAD];     // 16x17
    __shared__ float lwa[NHS + NHV * 3];    // 80
    __shared__ float ls[NPB * NS];          // 16x64
    __shared__ float lv[NPB * NV * 3];      // 16x48
    __shared__ float lf[NPB * 9];
    __shared__ float lp[NPB * 3];

    const int tid = threadIdx.x;
    // weights -> LDS (padded)
    for (int i = tid; i < NHS * NS; i += 256) lws[(i / NS) * WS_PAD + (i % NS)] = Ws[i];
    if (tid < NHV * NV) lwv[(tid / NV) * WV_PAD + (tid % NV)] = Wv[tid];
    if (tid < NHS) lwa[tid] = Wattn[s_off + tid];
    if (tid < NHV * 3) lwa[NHS + tid] = Wattn[v_off + tid];

    // node data -> LDS (fully coalesced float4 where possible)
    const int nbase = blockIdx.x * NPB;
    {
        const float4* sp = (const float4*)(node_s + (size_t)nbase * NS);
        ((float4*)ls)[tid] = sp[tid];                       // 256 float4 = 16x64
        const float4* vp = (const float4*)(node_v + (size_t)nbase * NV * 3);
        if (tid < NPB * NV * 3 / 4) ((float4*)lv)[tid] = vp[tid];   // 192 float4
        if (tid < NPB * 9) lf[tid] = frame[(size_t)nbase * 9 + tid];
        if (tid < NPB * 3) lp[tid] = pos[(size_t)nbase * 3 + tid];
    }
    __syncthreads();

    const int g = tid >> 4;      // node within block
    const int l = tid & 15;      // lane within node group
    const int n = nbase + g;
    if (n >= N) return;

    // scalar GEMV: lane l handles h = l and h = l+16
    const float4* sg = (const float4*)(ls + g * NS);
    float d0 = 0.f, d1 = 0.f;
    #pragma unroll
    for (int k4 = 0; k4 < NS / 4; k4++){
        float4 sv = sg[k4];
        float4 w0 = *(const float4*)(lws + l * WS_PAD + k4 * 4);
        float4 w1 = *(const float4*)(lws + (l + 16) * WS_PAD + k4 * 4);
        d0 += sv.x * w0.x + sv.y * w0.y + sv.z * w0.z + sv.w * w0.w;
        d1 += sv.x * w1.x + sv.y * w1.y + sv.z * w1.z + sv.w * w1.w;
    }
    float acc = silu_f(d0) * lwa[l] + silu_f(d1) * lwa[l + 16];

    // vector GEMV: lane l handles h = l; fvp[c] = sum_v v[vv][c] * Wv[l][vv]
    float a0 = 0.f, a1 = 0.f, a2 = 0.f;
    const float* vg = lv + g * NV * 3;
    #pragma unroll
    for (int vv = 0; vv < NV; vv++){
        float w = lwv[l * WV_PAD + vv];
        a0 += vg[vv * 3 + 0] * w;
        a1 += vg[vv * 3 + 1] * w;
        a2 += vg[vv * 3 + 2] * w;
    }
    const float* ff = lf + g * 9;
    #pragma unroll
    for (int c = 0; c < 3; c++){
        float t = a0 * ff[c] + a1 * ff[3 + c] + a2 * ff[6 + c];
        acc += silu_f(t) * lwa[NHS + l * 3 + c];
    }

    // reduce acc over the 16 lanes
    acc += __shfl_xor(acc, 8, 16);
    acc += __shfl_xor(acc, 4, 16);
    acc += __shfl_xor(acc, 2, 16);
    acc += __shfl_xor(acc, 1, 16);

    if (l < 4){
        const float* ps = lp + g * 3;
        float4 o;
        if (l == 0){
            float fpp0 = ps[0]*ff[0] + ps[1]*ff[3] + ps[2]*ff[6];
            float fpp1 = ps[0]*ff[1] + ps[1]*ff[4] + ps[2]*ff[7];
            float fpp2 = ps[0]*ff[2] + ps[1]*ff[5] + ps[2]*ff[8];
            o = make_float4(acc, fpp0, fpp1, fpp2);
        } else if (l == 1){
            o = make_float4(ff[0], ff[1], ff[2], ff[3]);
        } else if (l == 2){
            o = make_float4(ff[4], ff[5], ff[6], ff[7]);
        } else {
            o = make_float4(ff[8], ps[0], ps[1], ps[2]);
        }
        ((float4*)(pack + (size_t)n * 16))[l] = o;
    }
}

// Fused: raw -> exp -> ex[] + atomicAdd den  (no segment max; mathematically identical)
__global__ __launch_bounds__(256) void edge_fused_kernel(
    const int* __restrict__ idx,
    const float* __restrict__ packA,
    const float* __restrict__ packB,
    const float* __restrict__ Wattn,
    float* __restrict__ ex,
    float* __restrict__ den,
    int E)
{
    int e = blockIdx.x * 256 + threadIdx.x;
    if (e >= E) return;
    int i0 = idx[e];
    int i1 = idx[E + e];
    const float4* pa = (const float4*)(packA + (size_t)i0 * 16);
    const float4* pb = (const float4*)(packB + (size_t)i1 * 16);
    float4 a0 = pa[0], a1 = pa[1], a2 = pa[2], a3 = pa[3];
    float4 b0 = pb[0], b1 = pb[1], b2 = pb[2], b3 = pb[3];

    float r = a0.x + b0.x;
    float tp0=b3.y, tp1=b3.z, tp2=b3.w;   // to_pos
    float fp0=a3.y, fp1=a3.z, fp2=a3.w;   // from_pos
    // pdf[d] = to_pos . ff[:,d] - fpp[d]
    float pdf0 = tp0*a1.x + tp1*a1.w + tp2*a2.z - a0.y;
    float pdf1 = tp0*a1.y + tp1*a2.x + tp2*a2.w - a0.z;
    float pdf2 = tp0*a1.z + tp1*a2.y + tp2*a3.x - a0.w;
    // pdt[d] = from_pos . tf[:,d] - tpp[d]
    float pdt0 = fp0*b1.x + fp1*b1.w + fp2*b2.z - b0.y;
    float pdt1 = fp0*b1.y + fp1*b2.x + fp2*b2.w - b0.z;
    float pdt2 = fp0*b1.z + fp1*b2.y + fp2*b3.x - b0.w;

    r += silu_f(pdf0) * Wattn[112] + silu_f(pdf1) * Wattn[113] + silu_f(pdf2) * Wattn[114];
    r += silu_f(pdt0) * Wattn[163] + silu_f(pdt1) * Wattn[164] + silu_f(pdt2) * Wattn[165];

    float v = __expf(r);
    ex[e] = v;
    atomicAdd(&den[i0], v);
}

__global__ __launch_bounds__(256) void edge_out_kernel(
    const int* __restrict__ idx,
    const float* __restrict__ ex,
    const float* __restrict__ den,
    float* __restrict__ out,
    int E)
{
    int e = blockIdx.x * 256 + threadIdx.x;
    if (e >= E) return;
    int i0 = idx[e];
    out[e] = ex[e] / den[i0];
}

extern "C" void kernel_launch(void* const* d_in, const int* in_sizes, int n_in,
                              void* d_out, int out_size, void* d_ws, size_t ws_size,
                              hipStream_t stream)
{
    const float* from_s  = (const float*)d_in[0];
    const float* from_v  = (const float*)d_in[1];
    const float* to_s    = (const float*)d_in[2];
    const float* to_v    = (const float*)d_in[3];
    const float* from_fr = (const float*)d_in[4];
    const float* to_fr   = (const float*)d_in[5];
    const float* from_p  = (const float*)d_in[6];
    const float* to_p    = (const float*)d_in[7];
    const float* Wfs     = (const float*)d_in[8];
    const float* Wts     = (const float*)d_in[9];
    const float* Wfv     = (const float*)d_in[10];
    const float* Wtv     = (const float*)d_in[11];
    const float* Wattn   = (const float*)d_in[12];
    const int*   idx     = (const int*)d_in[13];

    int N = in_sizes[0] / NS;
    int E = in_sizes[13] / 2;
    float* out = (float*)d_out;

    char* ws = (char*)d_ws;
    size_t packBytes = (size_t)N * 16 * sizeof(float);
    float* packA = (float*)(ws);
    float* packB = (float*)(ws + packBytes);
    float* ex    = (float*)(ws + 2 * packBytes);
    float* den   = (float*)(ws + 2 * packBytes + (size_t)E * 4);

    hipMemsetAsync(den, 0, (size_t)N * 4, stream);

    dim3 ngrid((N + NPB - 1) / NPB, 2);
    node_pack_kernel<<<ngrid, 256, 0, stream>>>(
        from_s, from_v, from_fr, from_p,
        to_s, to_v, to_fr, to_p,
        Wfs, Wts, Wfv, Wtv, Wattn,
        packA, packB, N);

    int nb_e = (E + 255) / 256;
    edge_fused_kernel<<<nb_e, 256, 0, stream>>>(idx, packA, packB, Wattn, ex, den, E);
    edge_out_kernel<<<nb_e, 256, 0, stream>>>(idx, ex, den, out, E);
}

// Round 3
// 88.303 us; speedup vs baseline: 1.8312x; 1.0601x over previous
//
#include <hip/hip_runtime.h>
#include <math.h>

#define NS 64
#define NV 16
#define NHS 32
#define NHV 16
#define NPB 16           // nodes per block (16 lanes/node, 256 threads)
#define WS_PAD 68        // padded row stride for Ws in LDS (breaks bank conflict)
#define WV_PAD 17

__device__ __forceinline__ float silu_f(float x){ return x * (1.0f / (1.0f + __expf(-x))); }

// Per-node precompute: pack[n] = {A(n), fpp[3], frame[9], pos[3]}  (16 floats, 64B)
// blockIdx.y selects side (0 = from/A, 1 = to/B). Side 0 also zeroes den[n].
__global__ __launch_bounds__(256) void node_pack_kernel(
    const float* __restrict__ from_s, const float* __restrict__ from_v,
    const float* __restrict__ from_fr, const float* __restrict__ from_p,
    const float* __restrict__ to_s, const float* __restrict__ to_v,
    const float* __restrict__ to_fr, const float* __restrict__ to_p,
    const float* __restrict__ Wfs, const float* __restrict__ Wts,
    const float* __restrict__ Wfv, const float* __restrict__ Wtv,
    const float* __restrict__ Wattn,
    float* __restrict__ packA, float* __restrict__ packB,
    float* __restrict__ den,
    int N)
{
    const int side = blockIdx.y;
    const float* node_s = side ? to_s  : from_s;
    const float* node_v = side ? to_v  : from_v;
    const float* frame  = side ? to_fr : from_fr;
    const float* pos    = side ? to_p  : from_p;
    const float* Ws     = side ? Wts   : Wfs;
    const float* Wv     = side ? Wtv   : Wfv;
    const int    s_off  = side ? 32 : 0;
    const int    v_off  = side ? 115 : 64;
    float*       pack   = side ? packB : packA;

    __shared__ float lws[NHS * WS_PAD];     // 32x68
    __shared__ float lwv[NHV * WV_PAD];     // 16x17
    __shared__ float lwa[NHS + NHV * 3];    // 80
    __shared__ float ls[NPB * NS];          // 16x64
    __shared__ float lv[NPB * NV * 3];      // 16x48
    __shared__ float lf[NPB * 9];
    __shared__ float lp[NPB * 3];

    const int tid = threadIdx.x;
    // weights -> LDS (padded)
    for (int i = tid; i < NHS * NS; i += 256) lws[(i / NS) * WS_PAD + (i % NS)] = Ws[i];
    if (tid < NHV * NV) lwv[(tid / NV) * WV_PAD + (tid % NV)] = Wv[tid];
    if (tid < NHS) lwa[tid] = Wattn[s_off + tid];
    if (tid < NHV * 3) lwa[NHS + tid] = Wattn[v_off + tid];

    // node data -> LDS (fully coalesced float4 where possible)
    const int nbase = blockIdx.x * NPB;
    {
        const float4* sp = (const float4*)(node_s + (size_t)nbase * NS);
        ((float4*)ls)[tid] = sp[tid];                       // 256 float4 = 16x64
        const float4* vp = (const float4*)(node_v + (size_t)nbase * NV * 3);
        if (tid < NPB * NV * 3 / 4) ((float4*)lv)[tid] = vp[tid];   // 192 float4
        if (tid < NPB * 9) lf[tid] = frame[(size_t)nbase * 9 + tid];
        if (tid < NPB * 3) lp[tid] = pos[(size_t)nbase * 3 + tid];
        if (side == 0 && tid < NPB && nbase + tid < N) den[nbase + tid] = 0.0f;
    }
    __syncthreads();

    const int g = tid >> 4;      // node within block
    const int l = tid & 15;      // lane within node group
    const int n = nbase + g;
    if (n >= N) return;

    // scalar GEMV: lane l handles h = l and h = l+16
    const float4* sg = (const float4*)(ls + g * NS);
    float d0 = 0.f, d1 = 0.f;
    #pragma unroll
    for (int k4 = 0; k4 < NS / 4; k4++){
        float4 sv = sg[k4];
        float4 w0 = *(const float4*)(lws + l * WS_PAD + k4 * 4);
        float4 w1 = *(const float4*)(lws + (l + 16) * WS_PAD + k4 * 4);
        d0 += sv.x * w0.x + sv.y * w0.y + sv.z * w0.z + sv.w * w0.w;
        d1 += sv.x * w1.x + sv.y * w1.y + sv.z * w1.z + sv.w * w1.w;
    }
    float acc = silu_f(d0) * lwa[l] + silu_f(d1) * lwa[l + 16];

    // vector GEMV: lane l handles h = l
    float a0 = 0.f, a1 = 0.f, a2 = 0.f;
    const float* vg = lv + g * NV * 3;
    #pragma unroll
    for (int vv = 0; vv < NV; vv++){
        float w = lwv[l * WV_PAD + vv];
        a0 += vg[vv * 3 + 0] * w;
        a1 += vg[vv * 3 + 1] * w;
        a2 += vg[vv * 3 + 2] * w;
    }
    const float* ff = lf + g * 9;
    #pragma unroll
    for (int c = 0; c < 3; c++){
        float t = a0 * ff[c] + a1 * ff[3 + c] + a2 * ff[6 + c];
        acc += silu_f(t) * lwa[NHS + l * 3 + c];
    }

    // reduce acc over the 16 lanes
    acc += __shfl_xor(acc, 8, 16);
    acc += __shfl_xor(acc, 4, 16);
    acc += __shfl_xor(acc, 2, 16);
    acc += __shfl_xor(acc, 1, 16);

    if (l < 4){
        const float* ps = lp + g * 3;
        float4 o;
        if (l == 0){
            float fpp0 = ps[0]*ff[0] + ps[1]*ff[3] + ps[2]*ff[6];
            float fpp1 = ps[0]*ff[1] + ps[1]*ff[4] + ps[2]*ff[7];
            float fpp2 = ps[0]*ff[2] + ps[1]*ff[5] + ps[2]*ff[8];
            o = make_float4(acc, fpp0, fpp1, fpp2);
        } else if (l == 1){
            o = make_float4(ff[0], ff[1], ff[2], ff[3]);
        } else if (l == 2){
            o = make_float4(ff[4], ff[5], ff[6], ff[7]);
        } else {
            o = make_float4(ff[8], ps[0], ps[1], ps[2]);
        }
        ((float4*)(pack + (size_t)n * 16))[l] = o;
    }
}

// Fused: raw -> exp -> ex[] + HW atomic add to den (no segment max; mathematically identical)
__global__ __launch_bounds__(256) void edge_fused_kernel(
    const int* __restrict__ idx,
    const float* __restrict__ packA,
    const float* __restrict__ packB,
    const float* __restrict__ Wattn,
    float* __restrict__ ex,
    float* __restrict__ den,
    int E)
{
    int e = blockIdx.x * 256 + threadIdx.x;
    if (e >= E) return;
    int i0 = idx[e];
    int i1 = idx[E + e];
    const float4* pa = (const float4*)(packA + (size_t)i0 * 16);
    const float4* pb = (const float4*)(packB + (size_t)i1 * 16);
    float4 a0 = pa[0], a1 = pa[1], a2 = pa[2], a3 = pa[3];
    float4 b0 = pb[0], b1 = pb[1], b2 = pb[2], b3 = pb[3];

    float r = a0.x + b0.x;
    float tp0=b3.y, tp1=b3.z, tp2=b3.w;   // to_pos
    float fp0=a3.y, fp1=a3.z, fp2=a3.w;   // from_pos
    // pdf[d] = to_pos . ff[:,d] - fpp[d]
    float pdf0 = tp0*a1.x + tp1*a1.w + tp2*a2.z - a0.y;
    float pdf1 = tp0*a1.y + tp1*a2.x + tp2*a2.w - a0.z;
    float pdf2 = tp0*a1.z + tp1*a2.y + tp2*a3.x - a0.w;
    // pdt[d] = from_pos . tf[:,d] - tpp[d]
    float pdt0 = fp0*b1.x + fp1*b1.w + fp2*b2.z - b0.y;
    float pdt1 = fp0*b1.y + fp1*b2.x + fp2*b2.w - b0.z;
    float pdt2 = fp0*b1.z + fp1*b2.y + fp2*b3.x - b0.w;

    r += silu_f(pdf0) * Wattn[112] + silu_f(pdf1) * Wattn[113] + silu_f(pdf2) * Wattn[114];
    r += silu_f(pdt0) * Wattn[163] + silu_f(pdt1) * Wattn[164] + silu_f(pdt2) * Wattn[165];

    float v = __expf(r);
    ex[e] = v;
    unsafeAtomicAdd(&den[i0], v);   // HW global_atomic_add_f32, no CAS loop
}

__global__ __launch_bounds__(256) void edge_out_kernel(
    const int* __restrict__ idx,
    const float* __restrict__ ex,
    const float* __restrict__ den,
    float* __restrict__ out,
    int E)
{
    int e = blockIdx.x * 256 + threadIdx.x;
    if (e >= E) return;
    int i0 = idx[e];
    out[e] = ex[e] / den[i0];
}

extern "C" void kernel_launch(void* const* d_in, const int* in_sizes, int n_in,
                              void* d_out, int out_size, void* d_ws, size_t ws_size,
                              hipStream_t stream)
{
    const float* from_s  = (const float*)d_in[0];
    const float* from_v  = (const float*)d_in[1];
    const float* to_s    = (const float*)d_in[2];
    const float* to_v    = (const float*)d_in[3];
    const float* from_fr = (const float*)d_in[4];
    const float* to_fr   = (const float*)d_in[5];
    const float* from_p  = (const float*)d_in[6];
    const float* to_p    = (const float*)d_in[7];
    const float* Wfs     = (const float*)d_in[8];
    const float* Wts     = (const float*)d_in[9];
    const float* Wfv     = (const float*)d_in[10];
    const float* Wtv     = (const float*)d_in[11];
    const float* Wattn   = (const float*)d_in[12];
    const int*   idx     = (const int*)d_in[13];

    int N = in_sizes[0] / NS;
    int E = in_sizes[13] / 2;
    float* out = (float*)d_out;

    char* ws = (char*)d_ws;
    size_t packBytes = (size_t)N * 16 * sizeof(float);
    float* packA = (float*)(ws);
    float* packB = (float*)(ws + packBytes);
    float* ex    = (float*)(ws + 2 * packBytes);
    float* den   = (float*)(ws + 2 * packBytes + (size_t)E * 4);

    dim3 ngrid((N + NPB - 1) / NPB, 2);
    node_pack_kernel<<<ngrid, 256, 0, stream>>>(
        from_s, from_v, from_fr, from_p,
        to_s, to_v, to_fr, to_p,
        Wfs, Wts, Wfv, Wtv, Wattn,
        packA, packB, den, N);

    int nb_e = (E + 255) / 256;
    edge_fused_kernel<<<nb_e, 256, 0, stream>>>(idx, packA, packB, Wattn, ex, den, E);
    edge_out_kernel<<<nb_e, 256, 0, stream>>>(idx, ex, den, out, E);
}

// Round 4
// 86.963 us; speedup vs baseline: 1.8595x; 1.0154x over previous
//
#include <hip/hip_runtime.h>
#include <hip/hip_fp16.h>
#include <math.h>

#define NS 64
#define NV 16
#define NHS 32
#define NHV 16
#define NPB 16           // nodes per block (16 lanes/node, 256 threads)
#define WS_PAD 68        // padded row stride for Ws in LDS (breaks bank conflict)
#define WV_PAD 17

__device__ __forceinline__ float silu_f(float x){ return x * (1.0f / (1.0f + __expf(-x))); }

// pack two floats as half2 bit-cast into one float word
__device__ __forceinline__ float packh2(float a, float b){
    __half2 h = __floats2half2_rn(a, b);
    return __uint_as_float(*(unsigned*)&h);
}
__device__ __forceinline__ float2 unpackh2(float w){
    __half2 h = *(__half2*)&w;
    return __half22float2(h);
}

// Per-node precompute: pack[n] = 32B = {A fp32, ff[9]+pos[3] as fp16}
// blockIdx.y selects side (0 = from/A, 1 = to/B). Side 0 also zeroes den[n].
__global__ __launch_bounds__(256) void node_pack_kernel(
    const float* __restrict__ from_s, const float* __restrict__ from_v,
    const float* __restrict__ from_fr, const float* __restrict__ from_p,
    const float* __restrict__ to_s, const float* __restrict__ to_v,
    const float* __restrict__ to_fr, const float* __restrict__ to_p,
    const float* __restrict__ Wfs, const float* __restrict__ Wts,
    const float* __restrict__ Wfv, const float* __restrict__ Wtv,
    const float* __restrict__ Wattn,
    float* __restrict__ packA, float* __restrict__ packB,
    float* __restrict__ den,
    int N)
{
    const int side = blockIdx.y;
    const float* node_s = side ? to_s  : from_s;
    const float* node_v = side ? to_v  : from_v;
    const float* frame  = side ? to_fr : from_fr;
    const float* pos    = side ? to_p  : from_p;
    const float* Ws     = side ? Wts   : Wfs;
    const float* Wv     = side ? Wtv   : Wfv;
    const int    s_off  = side ? 32 : 0;
    const int    v_off  = side ? 115 : 64;
    float*       pack   = side ? packB : packA;

    __shared__ float lws[NHS * WS_PAD];     // 32x68
    __shared__ float lwv[NHV * WV_PAD];     // 16x17
    __shared__ float lwa[NHS + NHV * 3];    // 80
    __shared__ float ls[NPB * NS];          // 16x64
    __shared__ float lv[NPB * NV * 3];      // 16x48
    __shared__ float lf[NPB * 9];
    __shared__ float lp[NPB * 3];

    const int tid = threadIdx.x;
    for (int i = tid; i < NHS * NS; i += 256) lws[(i / NS) * WS_PAD + (i % NS)] = Ws[i];
    if (tid < NHV * NV) lwv[(tid / NV) * WV_PAD + (tid % NV)] = Wv[tid];
    if (tid < NHS) lwa[tid] = Wattn[s_off + tid];
    if (tid < NHV * 3) lwa[NHS + tid] = Wattn[v_off + tid];

    const int nbase = blockIdx.x * NPB;
    {
        const float4* sp = (const float4*)(node_s + (size_t)nbase * NS);
        ((float4*)ls)[tid] = sp[tid];
        const float4* vp = (const float4*)(node_v + (size_t)nbase * NV * 3);
        if (tid < NPB * NV * 3 / 4) ((float4*)lv)[tid] = vp[tid];
        if (tid < NPB * 9) lf[tid] = frame[(size_t)nbase * 9 + tid];
        if (tid < NPB * 3) lp[tid] = pos[(size_t)nbase * 3 + tid];
        if (side == 0 && tid < NPB && nbase + tid < N) den[nbase + tid] = 0.0f;
    }
    __syncthreads();

    const int g = tid >> 4;      // node within block
    const int l = tid & 15;      // lane within node group
    const int n = nbase + g;
    if (n >= N) return;

    // scalar GEMV: lane l handles h = l and h = l+16
    const float4* sg = (const float4*)(ls + g * NS);
    float d0 = 0.f, d1 = 0.f;
    #pragma unroll
    for (int k4 = 0; k4 < NS / 4; k4++){
        float4 sv = sg[k4];
        float4 w0 = *(const float4*)(lws + l * WS_PAD + k4 * 4);
        float4 w1 = *(const float4*)(lws + (l + 16) * WS_PAD + k4 * 4);
        d0 += sv.x * w0.x + sv.y * w0.y + sv.z * w0.z + sv.w * w0.w;
        d1 += sv.x * w1.x + sv.y * w1.y + sv.z * w1.z + sv.w * w1.w;
    }
    float acc = silu_f(d0) * lwa[l] + silu_f(d1) * lwa[l + 16];

    // vector GEMV: lane l handles h = l
    float a0 = 0.f, a1 = 0.f, a2 = 0.f;
    const float* vg = lv + g * NV * 3;
    #pragma unroll
    for (int vv = 0; vv < NV; vv++){
        float w = lwv[l * WV_PAD + vv];
        a0 += vg[vv * 3 + 0] * w;
        a1 += vg[vv * 3 + 1] * w;
        a2 += vg[vv * 3 + 2] * w;
    }
    const float* ff = lf + g * 9;
    #pragma unroll
    for (int c = 0; c < 3; c++){
        float t = a0 * ff[c] + a1 * ff[3 + c] + a2 * ff[6 + c];
        acc += silu_f(t) * lwa[NHS + l * 3 + c];
    }

    acc += __shfl_xor(acc, 8, 16);
    acc += __shfl_xor(acc, 4, 16);
    acc += __shfl_xor(acc, 2, 16);
    acc += __shfl_xor(acc, 1, 16);

    if (l < 2){
        const float* ps = lp + g * 3;
        float4 o;
        if (l == 0){
            o = make_float4(acc,
                            packh2(ff[0], ff[1]),
                            packh2(ff[2], ff[3]),
                            packh2(ff[4], ff[5]));
        } else {
            o = make_float4(packh2(ff[6], ff[7]),
                            packh2(ff[8], ps[0]),
                            packh2(ps[1], ps[2]),
                            0.0f);
        }
        ((float4*)(pack + (size_t)n * 8))[l] = o;
    }
}

// Fused: raw -> exp -> ex[] + HW atomic add to den
__global__ __launch_bounds__(256) void edge_fused_kernel(
    const int* __restrict__ idx,
    const float* __restrict__ packA,
    const float* __restrict__ packB,
    const float* __restrict__ Wattn,
    float* __restrict__ ex,
    float* __restrict__ den,
    int E)
{
    int e = blockIdx.x * 256 + threadIdx.x;
    if (e >= E) return;
    int i0 = idx[e];
    int i1 = idx[E + e];
    const float4* pa = (const float4*)(packA + (size_t)i0 * 8);
    const float4* pb = (const float4*)(packB + (size_t)i1 * 8);
    float4 a0 = pa[0], a1 = pa[1];
    float4 b0 = pb[0], b1 = pb[1];

    // unpack from-side: ff row-major [c][d], pos
    float2 t;
    t = unpackh2(a0.y); float af0 = t.x, af1 = t.y;
    t = unpackh2(a0.z); float af2 = t.x, af3 = t.y;
    t = unpackh2(a0.w); float af4 = t.x, af5 = t.y;
    t = unpackh2(a1.x); float af6 = t.x, af7 = t.y;
    t = unpackh2(a1.y); float af8 = t.x, ap0 = t.y;
    t = unpackh2(a1.z); float ap1 = t.x, ap2 = t.y;
    // unpack to-side
    t = unpackh2(b0.y); float bf0 = t.x, bf1 = t.y;
    t = unpackh2(b0.z); float bf2 = t.x, bf3 = t.y;
    t = unpackh2(b0.w); float bf4 = t.x, bf5 = t.y;
    t = unpackh2(b1.x); float bf6 = t.x, bf7 = t.y;
    t = unpackh2(b1.y); float bf8 = t.x, bp0 = t.y;
    t = unpackh2(b1.z); float bp1 = t.x, bp2 = t.y;

    float d0 = bp0 - ap0, d1 = bp1 - ap1, d2 = bp2 - ap2;  // to_pos - from_pos
    // pdf[d] = diff . ff[:,d] ; pdt[d] = -diff . tf[:,d]
    float pdf0 = d0*af0 + d1*af3 + d2*af6;
    float pdf1 = d0*af1 + d1*af4 + d2*af7;
    float pdf2 = d0*af2 + d1*af5 + d2*af8;
    float pdt0 = -(d0*bf0 + d1*bf3 + d2*bf6);
    float pdt1 = -(d0*bf1 + d1*bf4 + d2*bf7);
    float pdt2 = -(d0*bf2 + d1*bf5 + d2*bf8);

    float r = a0.x + b0.x;
    r += silu_f(pdf0) * Wattn[112] + silu_f(pdf1) * Wattn[113] + silu_f(pdf2) * Wattn[114];
    r += silu_f(pdt0) * Wattn[163] + silu_f(pdt1) * Wattn[164] + silu_f(pdt2) * Wattn[165];

    float v = __expf(r);
    ex[e] = v;
    unsafeAtomicAdd(&den[i0], v);
}

__global__ __launch_bounds__(256) void edge_out_kernel(
    const int* __restrict__ idx,
    const float* __restrict__ ex,
    const float* __restrict__ den,
    float* __restrict__ out,
    int E)
{
    int e = blockIdx.x * 256 + threadIdx.x;
    if (e >= E) return;
    int i0 = idx[e];
    out[e] = ex[e] / den[i0];
}

extern "C" void kernel_launch(void* const* d_in, const int* in_sizes, int n_in,
                              void* d_out, int out_size, void* d_ws, size_t ws_size,
                              hipStream_t stream)
{
    const float* from_s  = (const float*)d_in[0];
    const float* from_v  = (const float*)d_in[1];
    const float* to_s    = (const float*)d_in[2];
    const float* to_v    = (const float*)d_in[3];
    const float* from_fr = (const float*)d_in[4];
    const float* to_fr   = (const float*)d_in[5];
    const float* from_p  = (const float*)d_in[6];
    const float* to_p    = (const float*)d_in[7];
    const float* Wfs     = (const float*)d_in[8];
    const float* Wts     = (const float*)d_in[9];
    const float* Wfv     = (const float*)d_in[10];
    const float* Wtv     = (const float*)d_in[11];
    const float* Wattn   = (const float*)d_in[12];
    const int*   idx     = (const int*)d_in[13];

    int N = in_sizes[0] / NS;
    int E = in_sizes[13] / 2;
    float* out = (float*)d_out;

    char* ws = (char*)d_ws;
    size_t packBytes = (size_t)N * 8 * sizeof(float);   // 32B per node per side
    float* packA = (float*)(ws);
    float* packB = (float*)(ws + packBytes);
    float* ex    = (float*)(ws + 2 * packBytes);
    float* den   = (float*)(ws + 2 * packBytes + (size_t)E * 4);

    dim3 ngrid((N + NPB - 1) / NPB, 2);
    node_pack_kernel<<<ngrid, 256, 0, stream>>>(
        from_s, from_v, from_fr, from_p,
        to_s, to_v, to_fr, to_p,
        Wfs, Wts, Wfv, Wtv, Wattn,
        packA, packB, den, N);

    int nb_e = (E + 255) / 256;
    edge_fused_kernel<<<nb_e, 256, 0, stream>>>(idx, packA, packB, Wattn, ex, den, E);
    edge_out_kernel<<<nb_e, 256, 0, stream>>>(idx, ex, den, out, E);
}

// Round 5
// 83.910 us; speedup vs baseline: 1.9271x; 1.0364x over previous
//
#include <hip/hip_runtime.h>
#include <hip/hip_fp16.h>
#include <math.h>

#define NS 64
#define NV 16
#define NHS 32
#define NHV 16
#define NPB 16           // nodes per block (16 lanes/node, 256 threads)
#define WS_PAD 68        // padded row stride for Ws in LDS (breaks bank conflict)
#define WV_PAD 17
#define NXCD 8

__device__ __forceinline__ float silu_f(float x){ return x * (1.0f / (1.0f + __expf(-x))); }

__device__ __forceinline__ float packh2(float a, float b){
    __half2 h = __floats2half2_rn(a, b);
    return __uint_as_float(*(unsigned*)&h);
}
__device__ __forceinline__ float2 unpackh2(float w){
    __half2 h = *(__half2*)&w;
    return __half22float2(h);
}

// physical XCD id of the executing CU (uniform within a workgroup)
__device__ __forceinline__ int xcc_id(){
    unsigned x;
    asm("s_getreg_b32 %0, hwreg(HW_REG_XCC_ID)" : "=s"(x));
    return (int)(x & (NXCD - 1));
}

// fp32 atomic add executed in the XCD-local TCC (no sc bits -> cached in L2,
// coherent among all CUs of this XCD; cross-XCD safety via per-XCD den slices)
__device__ __forceinline__ void atomic_add_f32_l2(float* p, float v){
    asm volatile("global_atomic_add_f32 %0, %1, off"
                 : : "v"((unsigned long long)p), "v"(v) : "memory");
}

// Per-node precompute: pack[n] = 32B = {A fp32, ff[9]+pos[3] as fp16}
// blockIdx.y selects side (0 = from/A, 1 = to/B). Also zeroes den8.
__global__ __launch_bounds__(256) void node_pack_kernel(
    const float* __restrict__ from_s, const float* __restrict__ from_v,
    const float* __restrict__ from_fr, const float* __restrict__ from_p,
    const float* __restrict__ to_s, const float* __restrict__ to_v,
    const float* __restrict__ to_fr, const float* __restrict__ to_p,
    const float* __restrict__ Wfs, const float* __restrict__ Wts,
    const float* __restrict__ Wfv, const float* __restrict__ Wtv,
    const float* __restrict__ Wattn,
    float* __restrict__ packA, float* __restrict__ packB,
    float* __restrict__ den8,
    int N)
{
    const int side = blockIdx.y;
    const float* node_s = side ? to_s  : from_s;
    const float* node_v = side ? to_v  : from_v;
    const float* frame  = side ? to_fr : from_fr;
    const float* pos    = side ? to_p  : from_p;
    const float* Ws     = side ? Wts   : Wfs;
    const float* Wv     = side ? Wtv   : Wfv;
    const int    s_off  = side ? 32 : 0;
    const int    v_off  = side ? 115 : 64;
    float*       pack   = side ? packB : packA;

    __shared__ float lws[NHS * WS_PAD];
    __shared__ float lwv[NHV * WV_PAD];
    __shared__ float lwa[NHS + NHV * 3];
    __shared__ float ls[NPB * NS];
    __shared__ float lv[NPB * NV * 3];
    __shared__ float lf[NPB * 9];
    __shared__ float lp[NPB * 3];

    const int tid = threadIdx.x;
    for (int i = tid; i < NHS * NS; i += 256) lws[(i / NS) * WS_PAD + (i % NS)] = Ws[i];
    if (tid < NHV * NV) lwv[(tid / NV) * WV_PAD + (tid % NV)] = Wv[tid];
    if (tid < NHS) lwa[tid] = Wattn[s_off + tid];
    if (tid < NHV * 3) lwa[NHS + tid] = Wattn[v_off + tid];

    const int nbase = blockIdx.x * NPB;
    {
        const float4* sp = (const float4*)(node_s + (size_t)nbase * NS);
        ((float4*)ls)[tid] = sp[tid];
        const float4* vp = (const float4*)(node_v + (size_t)nbase * NV * 3);
        if (tid < NPB * NV * 3 / 4) ((float4*)lv)[tid] = vp[tid];
        if (tid < NPB * 9) lf[tid] = frame[(size_t)nbase * 9 + tid];
        if (tid < NPB * 3) lp[tid] = pos[(size_t)nbase * 3 + tid];
        // zero den8: each side's global threads cover 4N entries
        int g4 = blockIdx.x * 256 + tid;
        if (g4 < 4 * N) den8[(size_t)side * 4 * N + g4] = 0.0f;
    }
    __syncthreads();

    const int g = tid >> 4;
    const int l = tid & 15;
    const int n = nbase + g;
    if (n >= N) return;

    const float4* sg = (const float4*)(ls + g * NS);
    float d0 = 0.f, d1 = 0.f;
    #pragma unroll
    for (int k4 = 0; k4 < NS / 4; k4++){
        float4 sv = sg[k4];
        float4 w0 = *(const float4*)(lws + l * WS_PAD + k4 * 4);
        float4 w1 = *(const float4*)(lws + (l + 16) * WS_PAD + k4 * 4);
        d0 += sv.x * w0.x + sv.y * w0.y + sv.z * w0.z + sv.w * w0.w;
        d1 += sv.x * w1.x + sv.y * w1.y + sv.z * w1.z + sv.w * w1.w;
    }
    float acc = silu_f(d0) * lwa[l] + silu_f(d1) * lwa[l + 16];

    float a0 = 0.f, a1 = 0.f, a2 = 0.f;
    const float* vg = lv + g * NV * 3;
    #pragma unroll
    for (int vv = 0; vv < NV; vv++){
        float w = lwv[l * WV_PAD + vv];
        a0 += vg[vv * 3 + 0] * w;
        a1 += vg[vv * 3 + 1] * w;
        a2 += vg[vv * 3 + 2] * w;
    }
    const float* ff = lf + g * 9;
    #pragma unroll
    for (int c = 0; c < 3; c++){
        float t = a0 * ff[c] + a1 * ff[3 + c] + a2 * ff[6 + c];
        acc += silu_f(t) * lwa[NHS + l * 3 + c];
    }

    acc += __shfl_xor(acc, 8, 16);
    acc += __shfl_xor(acc, 4, 16);
    acc += __shfl_xor(acc, 2, 16);
    acc += __shfl_xor(acc, 1, 16);

    if (l < 2){
        const float* ps = lp + g * 3;
        float4 o;
        if (l == 0){
            o = make_float4(acc,
                            packh2(ff[0], ff[1]),
                            packh2(ff[2], ff[3]),
                            packh2(ff[4], ff[5]));
        } else {
            o = make_float4(packh2(ff[6], ff[7]),
                            packh2(ff[8], ps[0]),
                            packh2(ps[1], ps[2]),
                            0.0f);
        }
        ((float4*)(pack + (size_t)n * 8))[l] = o;
    }
}

// Fused: raw -> exp -> ex[] + XCD-local L2 atomic into den8[xcd]
__global__ __launch_bounds__(256) void edge_fused_kernel(
    const int* __restrict__ idx,
    const float* __restrict__ packA,
    const float* __restrict__ packB,
    const float* __restrict__ Wattn,
    float* __restrict__ ex,
    float* __restrict__ den8,
    int E, int N)
{
    int e = blockIdx.x * 256 + threadIdx.x;
    if (e >= E) return;
    int i0 = idx[e];
    int i1 = idx[E + e];
    const float4* pa = (const float4*)(packA + (size_t)i0 * 8);
    const float4* pb = (const float4*)(packB + (size_t)i1 * 8);
    float4 a0 = pa[0], a1 = pa[1];
    float4 b0 = pb[0], b1 = pb[1];

    float2 t;
    t = unpackh2(a0.y); float af0 = t.x, af1 = t.y;
    t = unpackh2(a0.z); float af2 = t.x, af3 = t.y;
    t = unpackh2(a0.w); float af4 = t.x, af5 = t.y;
    t = unpackh2(a1.x); float af6 = t.x, af7 = t.y;
    t = unpackh2(a1.y); float af8 = t.x, ap0 = t.y;
    t = unpackh2(a1.z); float ap1 = t.x, ap2 = t.y;
    t = unpackh2(b0.y); float bf0 = t.x, bf1 = t.y;
    t = unpackh2(b0.z); float bf2 = t.x, bf3 = t.y;
    t = unpackh2(b0.w); float bf4 = t.x, bf5 = t.y;
    t = unpackh2(b1.x); float bf6 = t.x, bf7 = t.y;
    t = unpackh2(b1.y); float bf8 = t.x, bp0 = t.y;
    t = unpackh2(b1.z); float bp1 = t.x, bp2 = t.y;

    float d0 = bp0 - ap0, d1 = bp1 - ap1, d2 = bp2 - ap2;
    float pdf0 = d0*af0 + d1*af3 + d2*af6;
    float pdf1 = d0*af1 + d1*af4 + d2*af7;
    float pdf2 = d0*af2 + d1*af5 + d2*af8;
    float pdt0 = -(d0*bf0 + d1*bf3 + d2*bf6);
    float pdt1 = -(d0*bf1 + d1*bf4 + d2*bf7);
    float pdt2 = -(d0*bf2 + d1*bf5 + d2*bf8);

    float r = a0.x + b0.x;
    r += silu_f(pdf0) * Wattn[112] + silu_f(pdf1) * Wattn[113] + silu_f(pdf2) * Wattn[114];
    r += silu_f(pdt0) * Wattn[163] + silu_f(pdt1) * Wattn[164] + silu_f(pdt2) * Wattn[165];

    float v = __expf(r);
    ex[e] = v;
    atomic_add_f32_l2(den8 + (size_t)xcc_id() * N + i0, v);
}

// collapse the 8 per-XCD partial sums
__global__ __launch_bounds__(256) void collapse_kernel(
    const float* __restrict__ den8,
    float* __restrict__ den,
    int N)
{
    int i = blockIdx.x * 256 + threadIdx.x;
    if (i >= N) return;
    float s = 0.f;
    #pragma unroll
    for (int x = 0; x < NXCD; x++) s += den8[(size_t)x * N + i];
    den[i] = s;
}

__global__ __launch_bounds__(256) void edge_out_kernel(
    const int* __restrict__ idx,
    const float* __restrict__ ex,
    const float* __restrict__ den,
    float* __restrict__ out,
    int E)
{
    int e = blockIdx.x * 256 + threadIdx.x;
    if (e >= E) return;
    int i0 = idx[e];
    out[e] = ex[e] / den[i0];
}

extern "C" void kernel_launch(void* const* d_in, const int* in_sizes, int n_in,
                              void* d_out, int out_size, void* d_ws, size_t ws_size,
                              hipStream_t stream)
{
    const float* from_s  = (const float*)d_in[0];
    const float* from_v  = (const float*)d_in[1];
    const float* to_s    = (const float*)d_in[2];
    const float* to_v    = (const float*)d_in[3];
    const float* from_fr = (const float*)d_in[4];
    const float* to_fr   = (const float*)d_in[5];
    const float* from_p  = (const float*)d_in[6];
    const float* to_p    = (const float*)d_in[7];
    const float* Wfs     = (const float*)d_in[8];
    const float* Wts     = (const float*)d_in[9];
    const float* Wfv     = (const float*)d_in[10];
    const float* Wtv     = (const float*)d_in[11];
    const float* Wattn   = (const float*)d_in[12];
    const int*   idx     = (const int*)d_in[13];

    int N = in_sizes[0] / NS;
    int E = in_sizes[13] / 2;
    float* out = (float*)d_out;

    char* ws = (char*)d_ws;
    size_t packBytes = (size_t)N * 8 * sizeof(float);   // 32B per node per side
    float* packA = (float*)(ws);
    float* packB = (float*)(ws + packBytes);
    float* ex    = (float*)(ws + 2 * packBytes);
    float* den8  = (float*)(ws + 2 * packBytes + (size_t)E * 4);
    float* den   = (float*)(ws + 2 * packBytes + (size_t)E * 4 + (size_t)NXCD * N * 4);

    dim3 ngrid((N + NPB - 1) / NPB, 2);
    node_pack_kernel<<<ngrid, 256, 0, stream>>>(
        from_s, from_v, from_fr, from_p,
        to_s, to_v, to_fr, to_p,
        Wfs, Wts, Wfv, Wtv, Wattn,
        packA, packB, den8, N);

    int nb_e = (E + 255) / 256;
    edge_fused_kernel<<<nb_e, 256, 0, stream>>>(idx, packA, packB, Wattn, ex, den8, E, N);
    collapse_kernel<<<(N + 255) / 256, 256, 0, stream>>>(den8, den, N);
    edge_out_kernel<<<nb_e, 256, 0, stream>>>(idx, ex, den, out, E);
}

// Round 6
// 80.523 us; speedup vs baseline: 2.0082x; 1.0421x over previous
//
#include <hip/hip_runtime.h>
#include <hip/hip_fp16.h>
#include <math.h>

#define NS 64
#define NV 16
#define NHS 32
#define NHV 16
#define NPB 16           // nodes per block in node_pack (16 lanes/node, 256 threads)
#define WS_PAD 68        // padded row stride for Ws in LDS (breaks bank conflict)
#define WV_PAD 17

// den_scan geometry
#define RANGES 32        // node ranges (one LDS den per range)
#define SPLITS 32        // edge-list splits
#define DP_STRIDE 50176  // padded per-split den stride (>= N, mult of 256)

__device__ __forceinline__ float silu_f(float x){ return x * (1.0f / (1.0f + __expf(-x))); }

__device__ __forceinline__ float packh2(float a, float b){
    __half2 h = __floats2half2_rn(a, b);
    return __uint_as_float(*(unsigned*)&h);
}
__device__ __forceinline__ float2 unpackh2(float w){
    __half2 h = *(__half2*)&w;
    return __half22float2(h);
}

// Per-node precompute: pack[n] = 32B = {A fp32, ff[9]+pos[3] as fp16}
__global__ __launch_bounds__(256) void node_pack_kernel(
    const float* __restrict__ from_s, const float* __restrict__ from_v,
    const float* __restrict__ from_fr, const float* __restrict__ from_p,
    const float* __restrict__ to_s, const float* __restrict__ to_v,
    const float* __restrict__ to_fr, const float* __restrict__ to_p,
    const float* __restrict__ Wfs, const float* __restrict__ Wts,
    const float* __restrict__ Wfv, const float* __restrict__ Wtv,
    const float* __restrict__ Wattn,
    float* __restrict__ packA, float* __restrict__ packB,
    int N)
{
    const int side = blockIdx.y;
    const float* node_s = side ? to_s  : from_s;
    const float* node_v = side ? to_v  : from_v;
    const float* frame  = side ? to_fr : from_fr;
    const float* pos    = side ? to_p  : from_p;
    const float* Ws     = side ? Wts   : Wfs;
    const float* Wv     = side ? Wtv   : Wfv;
    const int    s_off  = side ? 32 : 0;
    const int    v_off  = side ? 115 : 64;
    float*       pack   = side ? packB : packA;

    __shared__ float lws[NHS * WS_PAD];
    __shared__ float lwv[NHV * WV_PAD];
    __shared__ float lwa[NHS + NHV * 3];
    __shared__ float ls[NPB * NS];
    __shared__ float lv[NPB * NV * 3];
    __shared__ float lf[NPB * 9];
    __shared__ float lp[NPB * 3];

    const int tid = threadIdx.x;
    for (int i = tid; i < NHS * NS; i += 256) lws[(i / NS) * WS_PAD + (i % NS)] = Ws[i];
    if (tid < NHV * NV) lwv[(tid / NV) * WV_PAD + (tid % NV)] = Wv[tid];
    if (tid < NHS) lwa[tid] = Wattn[s_off + tid];
    if (tid < NHV * 3) lwa[NHS + tid] = Wattn[v_off + tid];

    const int nbase = blockIdx.x * NPB;
    {
        const float4* sp = (const float4*)(node_s + (size_t)nbase * NS);
        ((float4*)ls)[tid] = sp[tid];
        const float4* vp = (const float4*)(node_v + (size_t)nbase * NV * 3);
        if (tid < NPB * NV * 3 / 4) ((float4*)lv)[tid] = vp[tid];
        if (tid < NPB * 9) lf[tid] = frame[(size_t)nbase * 9 + tid];
        if (tid < NPB * 3) lp[tid] = pos[(size_t)nbase * 3 + tid];
    }
    __syncthreads();

    const int g = tid >> 4;
    const int l = tid & 15;
    const int n = nbase + g;
    if (n >= N) return;

    const float4* sg = (const float4*)(ls + g * NS);
    float d0 = 0.f, d1 = 0.f;
    #pragma unroll
    for (int k4 = 0; k4 < NS / 4; k4++){
        float4 sv = sg[k4];
        float4 w0 = *(const float4*)(lws + l * WS_PAD + k4 * 4);
        float4 w1 = *(const float4*)(lws + (l + 16) * WS_PAD + k4 * 4);
        d0 += sv.x * w0.x + sv.y * w0.y + sv.z * w0.z + sv.w * w0.w;
        d1 += sv.x * w1.x + sv.y * w1.y + sv.z * w1.z + sv.w * w1.w;
    }
    float acc = silu_f(d0) * lwa[l] + silu_f(d1) * lwa[l + 16];

    float a0 = 0.f, a1 = 0.f, a2 = 0.f;
    const float* vg = lv + g * NV * 3;
    #pragma unroll
    for (int vv = 0; vv < NV; vv++){
        float w = lwv[l * WV_PAD + vv];
        a0 += vg[vv * 3 + 0] * w;
        a1 += vg[vv * 3 + 1] * w;
        a2 += vg[vv * 3 + 2] * w;
    }
    const float* ff = lf + g * 9;
    #pragma unroll
    for (int c = 0; c < 3; c++){
        float t = a0 * ff[c] + a1 * ff[3 + c] + a2 * ff[6 + c];
        acc += silu_f(t) * lwa[NHS + l * 3 + c];
    }

    acc += __shfl_xor(acc, 8, 16);
    acc += __shfl_xor(acc, 4, 16);
    acc += __shfl_xor(acc, 2, 16);
    acc += __shfl_xor(acc, 1, 16);

    if (l < 2){
        const float* ps = lp + g * 3;
        float4 o;
        if (l == 0){
            o = make_float4(acc,
                            packh2(ff[0], ff[1]),
                            packh2(ff[2], ff[3]),
                            packh2(ff[4], ff[5]));
        } else {
            o = make_float4(packh2(ff[6], ff[7]),
                            packh2(ff[8], ps[0]),
                            packh2(ps[1], ps[2]),
                            0.0f);
        }
        ((float4*)(pack + (size_t)n * 8))[l] = o;
    }
}

// Fused: raw -> exp -> ex[] ; also emits u16 copy of idx0. NO atomics.
__global__ __launch_bounds__(256) void edge_fused_kernel(
    const int* __restrict__ idx,
    const float* __restrict__ packA,
    const float* __restrict__ packB,
    const float* __restrict__ Wattn,
    float* __restrict__ ex,
    unsigned short* __restrict__ i016,
    int E)
{
    int e = blockIdx.x * 256 + threadIdx.x;
    if (e >= E) return;
    int i0 = idx[e];
    int i1 = idx[E + e];
    const float4* pa = (const float4*)(packA + (size_t)i0 * 8);
    const float4* pb = (const float4*)(packB + (size_t)i1 * 8);
    float4 a0 = pa[0], a1 = pa[1];
    float4 b0 = pb[0], b1 = pb[1];

    float2 t;
    t = unpackh2(a0.y); float af0 = t.x, af1 = t.y;
    t = unpackh2(a0.z); float af2 = t.x, af3 = t.y;
    t = unpackh2(a0.w); float af4 = t.x, af5 = t.y;
    t = unpackh2(a1.x); float af6 = t.x, af7 = t.y;
    t = unpackh2(a1.y); float af8 = t.x, ap0 = t.y;
    t = unpackh2(a1.z); float ap1 = t.x, ap2 = t.y;
    t = unpackh2(b0.y); float bf0 = t.x, bf1 = t.y;
    t = unpackh2(b0.z); float bf2 = t.x, bf3 = t.y;
    t = unpackh2(b0.w); float bf4 = t.x, bf5 = t.y;
    t = unpackh2(b1.x); float bf6 = t.x, bf7 = t.y;
    t = unpackh2(b1.y); float bf8 = t.x, bp0 = t.y;
    t = unpackh2(b1.z); float bp1 = t.x, bp2 = t.y;

    float d0 = bp0 - ap0, d1 = bp1 - ap1, d2 = bp2 - ap2;
    float pdf0 = d0*af0 + d1*af3 + d2*af6;
    float pdf1 = d0*af1 + d1*af4 + d2*af7;
    float pdf2 = d0*af2 + d1*af5 + d2*af8;
    float pdt0 = -(d0*bf0 + d1*bf3 + d2*bf6);
    float pdt1 = -(d0*bf1 + d1*bf4 + d2*bf7);
    float pdt2 = -(d0*bf2 + d1*bf5 + d2*bf8);

    float r = a0.x + b0.x;
    r += silu_f(pdf0) * Wattn[112] + silu_f(pdf1) * Wattn[113] + silu_f(pdf2) * Wattn[114];
    r += silu_f(pdt0) * Wattn[163] + silu_f(pdt1) * Wattn[164] + silu_f(pdt2) * Wattn[165];

    ex[e] = __expf(r);
    i016[e] = (unsigned short)i0;
}

// Ownership-partitioned segmented sum: block (range r, split s) scans its edge
// slice, LDS-accumulates ex for nodes in its range, writes a non-atomic partial.
__global__ __launch_bounds__(512) void den_scan_kernel(
    const unsigned short* __restrict__ i016,
    const float* __restrict__ ex,
    float* __restrict__ den_part,     // [SPLITS][DP_STRIDE]
    int E, int N)
{
    const int r = blockIdx.x & (RANGES - 1);
    const int s = blockIdx.x >> 5;            // log2(RANGES)
    const int rn = (N + RANGES - 1) / RANGES; // nodes per range
    const int base = r * rn;

    extern __shared__ float lden[];           // rn floats
    for (int i = threadIdx.x; i < rn; i += 512) lden[i] = 0.0f;
    __syncthreads();

    const int es = (E + SPLITS - 1) / SPLITS;
    const int e0 = s * es;
    const int e1 = min(e0 + es, E);

    #pragma unroll 4
    for (int e = e0 + threadIdx.x; e < e1; e += 512){
        unsigned d = (unsigned)i016[e] - (unsigned)base;
        if (d < (unsigned)rn){
            atomicAdd(&lden[d], ex[e]);       // LDS atomic: fast HW path
        }
    }
    __syncthreads();

    float* dp = den_part + (size_t)s * DP_STRIDE + base;
    for (int i = threadIdx.x; i < rn && base + i < N; i += 512) dp[i] = lden[i];
}

// collapse the SPLITS partial sums
__global__ __launch_bounds__(256) void collapse_kernel(
    const float* __restrict__ den_part,
    float* __restrict__ den,
    int N)
{
    int i = blockIdx.x * 256 + threadIdx.x;
    if (i >= N) return;
    float sum = 0.f;
    #pragma unroll
    for (int s = 0; s < SPLITS; s++) sum += den_part[(size_t)s * DP_STRIDE + i];
    den[i] = sum;
}

__global__ __launch_bounds__(256) void edge_out_kernel(
    const unsigned short* __restrict__ i016,
    const float* __restrict__ ex,
    const float* __restrict__ den,
    float* __restrict__ out,
    int E)
{
    int e = blockIdx.x * 256 + threadIdx.x;
    if (e >= E) return;
    int i0 = (int)i016[e];
    out[e] = ex[e] / den[i0];
}

extern "C" void kernel_launch(void* const* d_in, const int* in_sizes, int n_in,
                              void* d_out, int out_size, void* d_ws, size_t ws_size,
                              hipStream_t stream)
{
    const float* from_s  = (const float*)d_in[0];
    const float* from_v  = (const float*)d_in[1];
    const float* to_s    = (const float*)d_in[2];
    const float* to_v    = (const float*)d_in[3];
    const float* from_fr = (const float*)d_in[4];
    const float* to_fr   = (const float*)d_in[5];
    const float* from_p  = (const float*)d_in[6];
    const float* to_p    = (const float*)d_in[7];
    const float* Wfs     = (const float*)d_in[8];
    const float* Wts     = (const float*)d_in[9];
    const float* Wfv     = (const float*)d_in[10];
    const float* Wtv     = (const float*)d_in[11];
    const float* Wattn   = (const float*)d_in[12];
    const int*   idx     = (const int*)d_in[13];

    int N = in_sizes[0] / NS;
    int E = in_sizes[13] / 2;
    float* out = (float*)d_out;

    char* ws = (char*)d_ws;
    size_t packBytes = (size_t)N * 8 * sizeof(float);            // 1.6MB each
    float*          packA    = (float*)(ws);
    float*          packB    = (float*)(ws + packBytes);
    float*          ex       = (float*)(ws + 2 * packBytes);
    float*          den_part = (float*)(ws + 2 * packBytes + (size_t)E * 4);
    float*          den      = (float*)(ws + 2 * packBytes + (size_t)E * 4
                                         + (size_t)SPLITS * DP_STRIDE * 4);
    unsigned short* i016     = (unsigned short*)(ws + 2 * packBytes + (size_t)E * 4
                                         + (size_t)SPLITS * DP_STRIDE * 4
                                         + (size_t)N * 4 + 256);

    dim3 ngrid((N + NPB - 1) / NPB, 2);
    node_pack_kernel<<<ngrid, 256, 0, stream>>>(
        from_s, from_v, from_fr, from_p,
        to_s, to_v, to_fr, to_p,
        Wfs, Wts, Wfv, Wtv, Wattn,
        packA, packB, N);

    int nb_e = (E + 255) / 256;
    edge_fused_kernel<<<nb_e, 256, 0, stream>>>(idx, packA, packB, Wattn, ex, i016, E);

    int rn = (N + RANGES - 1) / RANGES;
    size_t lds_bytes = (size_t)rn * sizeof(float);
    den_scan_kernel<<<RANGES * SPLITS, 512, lds_bytes, stream>>>(i016, ex, den_part, E, N);
    collapse_kernel<<<(N + 255) / 256, 256, 0, stream>>>(den_part, den, N);
    edge_out_kernel<<<nb_e, 256, 0, stream>>>(i016, ex, den, out, E);
}